// Round 6
// baseline (2217.894 us; speedup 1.0000x reference)
//
#include <hip/hip_runtime.h>
#include <hip/hip_bf16.h>

#define DINL __device__ __forceinline__

namespace {

typedef unsigned long long u64;

constexpr int Tn = 256;   // sequence length
constexpr int Bn = 64;    // batch
constexpr int HDn = 256;  // per-direction hidden
constexpr int Kt = 20;    // tagset
constexpr int STOPt = 19;
constexpr int STARTt = 18;
constexpr float NEGV = -10000.0f;

DINL float sigm(float x) { return 1.0f / (1.0f + __expf(-x)); }
DINL float tanh_f(float x) {
  float ax = fabsf(x);
  float e = __expf(-2.0f * ax);       // in (0,1]
  float t = (1.0f - e) / (1.0f + e);
  return x < 0.0f ? -t : t;
}

DINL void agent_st64(u64* p, u64 v) {
  __hip_atomic_store(p, v, __ATOMIC_RELAXED, __HIP_MEMORY_SCOPE_AGENT);
}

// ---------------- K0: clear h-epoch pairs (replay safety) --------------------
__global__ void k_clear(uint4* p) {
  size_t i = (size_t)blockIdx.x * 256 + threadIdx.x;   // 4096*256 threads
  const uint4 z = {0, 0, 0, 0};
#pragma unroll
  for (int j = 0; j < 4; ++j) p[i + (size_t)j * 4096 * 256] = z;
}

// ---------------- K1: transpose/concat W_ih into Wt[300][2048] ---------------
__global__ void k_wt(const float* __restrict__ wf, const float* __restrict__ wb,
                     float* __restrict__ Wt) {
  int idx = blockIdx.x * 256 + threadIdx.x;
  if (idx >= 300 * 2048) return;
  int k = idx >> 11, n = idx & 2047;
  const float* w = (n < 1024) ? wf : wb;
  int nn = n & 1023;
  Wt[idx] = w[nn * 300 + k];
}

// ---------------- K2: x_proj = gather(embeds) @ W_ih^T + b -------------------
// C[16384, 2048], row m = t*64 + b. Tile 64(M) x 128(N), BK=20, 256 threads.
__global__ __launch_bounds__(256) void k_xproj(
    const int* __restrict__ sentence, const float* __restrict__ table,
    const float* __restrict__ Wt, const float* __restrict__ b_f,
    const float* __restrict__ b_b, float* __restrict__ xproj) {
  __shared__ float As[20][68];    // A^T tile: [kk][row(b)]
  __shared__ float Bs[20][136];   // [kk][col]
  __shared__ int tok[64];

  int tid = threadIdx.x;
  int t = blockIdx.x;             // one time index per M-tile (64 rows = 64 b)
  int n0 = blockIdx.y * 128;

  if (tid < 64) tok[tid] = sentence[tid * Tn + t];  // sentence[b][t]
  __syncthreads();

  int ty = tid >> 4, tx = tid & 15;   // 16x16 threads; micro-tile 4(M) x 8(N)
  float acc[4][8];
#pragma unroll
  for (int i = 0; i < 4; ++i)
#pragma unroll
    for (int j = 0; j < 8; ++j) acc[i][j] = 0.0f;

  for (int k0 = 0; k0 < 300; k0 += 20) {
#pragma unroll
    for (int i = 0; i < 5; ++i) {
      int idx = i * 256 + tid;        // 0..1279
      int r = idx / 20, kk = idx % 20;
      As[kk][r] = table[tok[r] * 300 + k0 + kk];
    }
#pragma unroll
    for (int i = 0; i < 10; ++i) {
      int idx = i * 256 + tid;        // 0..2559
      int kk = idx >> 7, c = idx & 127;
      Bs[kk][c] = Wt[(k0 + kk) * 2048 + n0 + c];
    }
    __syncthreads();
#pragma unroll
    for (int kk = 0; kk < 20; ++kk) {
      float4 a4 = *(const float4*)&As[kk][ty * 4];
      float4 b4a = *(const float4*)&Bs[kk][tx * 8];
      float4 b4b = *(const float4*)&Bs[kk][tx * 8 + 4];
      float av[4] = {a4.x, a4.y, a4.z, a4.w};
      float bvv[8] = {b4a.x, b4a.y, b4a.z, b4a.w, b4b.x, b4b.y, b4b.z, b4b.w};
#pragma unroll
      for (int i = 0; i < 4; ++i)
#pragma unroll
        for (int j = 0; j < 8; ++j) acc[i][j] += av[i] * bvv[j];
    }
    __syncthreads();
  }

  float bias[8];
#pragma unroll
  for (int j = 0; j < 8; ++j) {
    int n = n0 + tx * 8 + j;
    bias[j] = (n < 1024) ? b_f[n] : b_b[n - 1024];
  }
#pragma unroll
  for (int i = 0; i < 4; ++i) {
    size_t m = (size_t)t * 64 + ty * 4 + i;   // row = (t, b=ty*4+i)
    float* dst = &xproj[m * 2048 + n0 + tx * 8];
    float4 v0 = {acc[i][0] + bias[0], acc[i][1] + bias[1], acc[i][2] + bias[2],
                 acc[i][3] + bias[3]};
    float4 v1 = {acc[i][4] + bias[4], acc[i][5] + bias[5], acc[i][6] + bias[6],
                 acc[i][7] + bias[7]};
    *(float4*)dst = v0;
    *(float4*)(dst + 4) = v1;
  }
}

// ---------------- K3: persistent bidirectional LSTM --------------------------
// 256 blocks x 128 thr, geometry identical to round 4. ONLY change vs r4: the
// poll batches 16 global_load_dwordx4 sc1 + ONE s_waitcnt inside a SINGLE asm
// block (16 early-clobber outputs), instead of 32 serialized atomic loads.
__global__ __launch_bounds__(128) void k_lstm(
    const float* __restrict__ whh_f, const float* __restrict__ whh_b,
    const float* __restrict__ xproj, u64* __restrict__ h_ep) {
  __shared__ __align__(16) float hl[16 * 256];  // 16 batches x 256 k (16KB)

  int tid = threadIdx.x;
  int bid = blockIdx.x;
  int gid = bid & 7;        // dir = gid>>2, bg = gid&3 (XCD-affine grouping)
  int s = bid >> 3;         // slice 0..31 (8 hidden cols each)
  int dir = gid >> 2;
  int bg = gid & 3;
  const float* whh = dir ? whh_b : whh_f;

  int c = tid >> 4;         // hidden-col within slice, 0..7
  int kc = tid & 15;        // k-partition (16 interleaved granules of 4)

  // --- W into registers: w4[gate][jj] = W[g*256 + s*8 + c][ (kc+16jj)*4 .. +4 )
  float4 w4[4][4];
#pragma unroll
  for (int g = 0; g < 4; ++g) {
    const float* src = whh + ((size_t)(g * 256 + s * 8 + c)) * 256;
#pragma unroll
    for (int jj = 0; jj < 4; ++jj)
      w4[g][jj] = *(const float4*)(src + ((kc + (jj << 4)) << 2));
  }

  float c_reg = 0.0f;

  for (int st = 0; st < Tn; ++st) {
    int xt = dir ? (Tn - 1 - st) : st;

    // prefetch x-projection gates (independent -> overlaps the poll)
    float xp[4];
    {
      size_t base = ((size_t)(xt * 64 + bg * 16 + kc)) * 2048 + dir * 1024 +
                    s * 8 + c;
#pragma unroll
      for (int g = 0; g < 4; ++g) xp[g] = xproj[base + g * 256];
    }

    float acc[16][4];
#pragma unroll
    for (int b = 0; b < 16; ++b)
#pragma unroll
      for (int g = 0; g < 4; ++g) acc[b][g] = 0.0f;

    if (st > 0) {
      int pt = dir ? (xt + 1) : (xt - 1);
      const u64* hsrc =
          h_ep + ((size_t)(dir * Tn + pt) * 64 + bg * 16) * 256;
      // thread's 32 pairs: granules (tid + 128*i), i=0..7; each granule = 4
      // pairs = 32B = two dwordx4. Base byte offset tid*32, i-stride 4096B.
      const char* tb = (const char*)hsrc + (size_t)tid * 32;
      const char* p0 = tb;
      const char* p1 = tb + 4096;
      const char* p2 = tb + 8192;
      const char* p3 = tb + 12288;
      const char* p4 = tb + 16384;
      const char* p5 = tb + 20480;
      const char* p6 = tb + 24576;
      const char* p7 = tb + 28672;
      uint4 q0, q1, q2, q3, q4, q5, q6, q7;
      uint4 q8, q9, q10, q11, q12, q13, q14, q15;
      unsigned tgt = (unsigned)st;
      for (;;) {
        // 16 loads issued back-to-back + ONE wait, all inside one asm block:
        // outputs only valid after the waitcnt -> no use can precede it.
        asm volatile(
            "global_load_dwordx4 %0, %16, off sc1\n\t"
            "global_load_dwordx4 %1, %16, off offset:16 sc1\n\t"
            "global_load_dwordx4 %2, %17, off sc1\n\t"
            "global_load_dwordx4 %3, %17, off offset:16 sc1\n\t"
            "global_load_dwordx4 %4, %18, off sc1\n\t"
            "global_load_dwordx4 %5, %18, off offset:16 sc1\n\t"
            "global_load_dwordx4 %6, %19, off sc1\n\t"
            "global_load_dwordx4 %7, %19, off offset:16 sc1\n\t"
            "global_load_dwordx4 %8, %20, off sc1\n\t"
            "global_load_dwordx4 %9, %20, off offset:16 sc1\n\t"
            "global_load_dwordx4 %10, %21, off sc1\n\t"
            "global_load_dwordx4 %11, %21, off offset:16 sc1\n\t"
            "global_load_dwordx4 %12, %22, off sc1\n\t"
            "global_load_dwordx4 %13, %22, off offset:16 sc1\n\t"
            "global_load_dwordx4 %14, %23, off sc1\n\t"
            "global_load_dwordx4 %15, %23, off offset:16 sc1\n\t"
            "s_waitcnt vmcnt(0)"
            : "=&v"(q0), "=&v"(q1), "=&v"(q2), "=&v"(q3), "=&v"(q4),
              "=&v"(q5), "=&v"(q6), "=&v"(q7), "=&v"(q8), "=&v"(q9),
              "=&v"(q10), "=&v"(q11), "=&v"(q12), "=&v"(q13), "=&v"(q14),
              "=&v"(q15)
            : "v"(p0), "v"(p1), "v"(p2), "v"(p3), "v"(p4), "v"(p5), "v"(p6),
              "v"(p7));
        bool ok = (q0.y == tgt) & (q0.w == tgt) & (q1.y == tgt) & (q1.w == tgt) &
                  (q2.y == tgt) & (q2.w == tgt) & (q3.y == tgt) & (q3.w == tgt) &
                  (q4.y == tgt) & (q4.w == tgt) & (q5.y == tgt) & (q5.w == tgt) &
                  (q6.y == tgt) & (q6.w == tgt) & (q7.y == tgt) & (q7.w == tgt) &
                  (q8.y == tgt) & (q8.w == tgt) & (q9.y == tgt) & (q9.w == tgt) &
                  (q10.y == tgt) & (q10.w == tgt) & (q11.y == tgt) &
                  (q11.w == tgt) & (q12.y == tgt) & (q12.w == tgt) &
                  (q13.y == tgt) & (q13.w == tgt) & (q14.y == tgt) &
                  (q14.w == tgt) & (q15.y == tgt) & (q15.w == tgt);
        if (ok) break;
        __builtin_amdgcn_s_sleep(2);
      }
      __syncthreads();  // B1: previous step's hl readers done
      // stage: granule i at float4 index (tid + 128*i) — lane-linear, 0-conflict
      {
        float4 gv;
        gv.x = __uint_as_float(q0.x);  gv.y = __uint_as_float(q0.z);
        gv.z = __uint_as_float(q1.x);  gv.w = __uint_as_float(q1.z);
        *(float4*)&hl[(tid + 0 * 128) << 2] = gv;
        gv.x = __uint_as_float(q2.x);  gv.y = __uint_as_float(q2.z);
        gv.z = __uint_as_float(q3.x);  gv.w = __uint_as_float(q3.z);
        *(float4*)&hl[(tid + 1 * 128) << 2] = gv;
        gv.x = __uint_as_float(q4.x);  gv.y = __uint_as_float(q4.z);
        gv.z = __uint_as_float(q5.x);  gv.w = __uint_as_float(q5.z);
        *(float4*)&hl[(tid + 2 * 128) << 2] = gv;
        gv.x = __uint_as_float(q6.x);  gv.y = __uint_as_float(q6.z);
        gv.z = __uint_as_float(q7.x);  gv.w = __uint_as_float(q7.z);
        *(float4*)&hl[(tid + 3 * 128) << 2] = gv;
        gv.x = __uint_as_float(q8.x);  gv.y = __uint_as_float(q8.z);
        gv.z = __uint_as_float(q9.x);  gv.w = __uint_as_float(q9.z);
        *(float4*)&hl[(tid + 4 * 128) << 2] = gv;
        gv.x = __uint_as_float(q10.x); gv.y = __uint_as_float(q10.z);
        gv.z = __uint_as_float(q11.x); gv.w = __uint_as_float(q11.z);
        *(float4*)&hl[(tid + 5 * 128) << 2] = gv;
        gv.x = __uint_as_float(q12.x); gv.y = __uint_as_float(q12.z);
        gv.z = __uint_as_float(q13.x); gv.w = __uint_as_float(q13.z);
        *(float4*)&hl[(tid + 6 * 128) << 2] = gv;
        gv.x = __uint_as_float(q14.x); gv.y = __uint_as_float(q14.z);
        gv.z = __uint_as_float(q15.x); gv.w = __uint_as_float(q15.z);
        *(float4*)&hl[(tid + 7 * 128) << 2] = gv;
      }
      __syncthreads();  // B2: hl ready

      // GEMV: each b128 read feeds 16 FMAs (4 gates x 4 k)
#pragma unroll
      for (int b = 0; b < 16; ++b) {
#pragma unroll
        for (int jj = 0; jj < 4; ++jj) {
          float4 hv = *(const float4*)&hl[b * 256 + ((kc + (jj << 4)) << 2)];
#pragma unroll
          for (int g = 0; g < 4; ++g) {
            acc[b][g] += w4[g][jj].x * hv.x + w4[g][jj].y * hv.y +
                         w4[g][jj].z * hv.z + w4[g][jj].w * hv.w;
          }
        }
      }
    }

    // register-halving butterfly over kc: after round r, entry ii holds
    // b = ii*2^(r+1) + (kc & (2^(r+1)-1)); final: acc[0][g] = gates of b=kc.
#pragma unroll
    for (int r = 0; r < 4; ++r) {
      int m = 1 << r;
      int kb = (kc >> r) & 1;
#pragma unroll
      for (int ii = 0; ii < (16 >> (r + 1)); ++ii) {
#pragma unroll
        for (int g = 0; g < 4; ++g) {
          float e = acc[2 * ii][g], o = acc[2 * ii + 1][g];
          float kept = kb ? o : e;
          float sent = kb ? e : o;
          acc[ii][g] = kept + __shfl_xor(sent, m, 64);
        }
      }
    }

    // update: thread owns (b = kc, col = s*8 + c); gate order i,f,g,o
    {
      float gi = acc[0][0] + xp[0];
      float gf = acc[0][1] + xp[1];
      float gg = acc[0][2] + xp[2];
      float go = acc[0][3] + xp[3];
      c_reg = sigm(gf) * c_reg + sigm(gi) * tanh_f(gg);
      float h = sigm(go) * tanh_f(c_reg);
      u64 pk = ((u64)(unsigned)(st + 1) << 32) | (u64)__float_as_uint(h);
      agent_st64(&h_ep[((size_t)(dir * Tn + xt) * 64 + bg * 16 + kc) * 256 +
                       s * 8 + c],
                 pk);
    }
  }
}

// ---------------- K4: feats = concat(hf,hb) @ W_out^T + b_out ----------------
__global__ __launch_bounds__(256) void k_feats(const u64* __restrict__ h_ep,
                                               const float* __restrict__ Wout,
                                               const float* __restrict__ bout,
                                               float* __restrict__ feats) {
  __shared__ float Wl[20 * 512];   // 40KB
  __shared__ float hlf[64 * 256];  // 64KB, XOR-swizzled

  int tid = threadIdx.x;
  int t = blockIdx.x;
  for (int i = tid; i < 20 * 512; i += 256) Wl[i] = Wout[i];

  float acc[5] = {0, 0, 0, 0, 0};
  int b = tid & 63, kg5 = tid >> 6;
  int swz = b & 7;

  for (int d = 0; d < 2; ++d) {
    __syncthreads();
    const u64* hsrc = h_ep + ((size_t)(d * Tn + t)) * 64 * 256;
#pragma unroll 8
    for (int i = 0; i < 64; ++i) {
      int idx = i * 256 + tid;
      int hb = idx >> 8, k = idx & 255;
      u64 pk = hsrc[idx];
      hlf[hb * 256 + 4 * ((k >> 2) ^ (hb & 7)) + (k & 3)] =
          __uint_as_float((unsigned)pk);
    }
    __syncthreads();
    for (int jg = 0; jg < 64; ++jg) {
      float4 hv = *(const float4*)&hlf[b * 256 + 4 * (jg ^ swz)];
#pragma unroll
      for (int kk = 0; kk < 5; ++kk) {
        int krow = kg5 * 5 + kk;
        float4 wvv = *(const float4*)&Wl[krow * 512 + d * 256 + jg * 4];
        acc[kk] += hv.x * wvv.x + hv.y * wvv.y + hv.z * wvv.z + hv.w * wvv.w;
      }
    }
  }
#pragma unroll
  for (int kk = 0; kk < 5; ++kk) {
    int krow = kg5 * 5 + kk;
    feats[((size_t)b * Tn + t) * Kt + krow] = acc[kk] + bout[krow];
  }
}

// ---------------- K5: Viterbi decode, one wave per batch element -------------
__global__ __launch_bounds__(64) void k_viterbi(const float* __restrict__ feats,
                                                const float* __restrict__ trans,
                                                const int* __restrict__ length,
                                                float* __restrict__ out) {
  __shared__ float tr[400];
  __shared__ float fv[20];
  __shared__ float term[20];
  __shared__ unsigned char bps[256][20];

  int b = blockIdx.x;
  int lane = threadIdx.x;
  for (int i = lane; i < 400; i += 64) tr[i] = trans[i];
  if (lane < 20) fv[lane] = (lane == STARTt) ? 0.0f : NEGV;
  int len = length[b];
  __syncthreads();

  for (int t = 0; t < Tn; ++t) {
    float nf = 0.0f;
    int bp = 0;
    if (lane < 20) {
      if (t < len) {
        float vmax = -3.4e38f;
        int pb = 0;
#pragma unroll
        for (int p = 0; p < 20; ++p) {
          float v = fv[p] + tr[lane * 20 + p];
          if (v > vmax) { vmax = v; pb = p; }   // strict > == first-argmax
        }
        nf = vmax + feats[((size_t)b * Tn + t) * Kt + lane];
        bp = pb;
      } else {
        nf = fv[lane];
        bp = lane;
      }
    }
    __syncthreads();
    if (lane < 20) {
      fv[lane] = nf;
      bps[t][lane] = (unsigned char)bp;
    }
    __syncthreads();
  }

  if (lane < 20) term[lane] = fv[lane] + tr[STOPt * 20 + lane];
  __syncthreads();
  if (lane == 0) {
    float smax = term[0];
    int last = 0;
    for (int p = 1; p < 20; ++p)
      if (term[p] > smax) { smax = term[p]; last = p; }
    out[b] = smax;                     // viterbi score
    int tag = last;
    for (int t = Tn - 1; t >= 0; --t) {
      out[64 + b * Tn + t] = (float)tag;
      tag = bps[t][tag];
    }
  }
}

}  // namespace

extern "C" void kernel_launch(void* const* d_in, const int* in_sizes, int n_in,
                              void* d_out, int out_size, void* d_ws,
                              size_t ws_size, hipStream_t stream) {
  const int* sentence = (const int*)d_in[0];
  const int* length = (const int*)d_in[1];
  const float* table = (const float*)d_in[2];
  const float* w_ih_f = (const float*)d_in[3];
  const float* w_hh_f = (const float*)d_in[4];
  const float* b_f = (const float*)d_in[5];
  const float* w_ih_b = (const float*)d_in[6];
  const float* w_hh_b = (const float*)d_in[7];
  const float* b_b = (const float*)d_in[8];
  const float* W_out = (const float*)d_in[9];
  const float* b_out = (const float*)d_in[10];
  const float* trans = (const float*)d_in[11];
  float* out = (float*)d_out;

  // workspace layout (floats)
  float* ws = (float*)d_ws;
  float* xproj = ws;                                  // 33,554,432 f
  u64* h_ep = (u64*)(ws + (size_t)33554432);          // 8,388,608 u64 (67 MB)
  float* Wt = ws + (size_t)33554432 + 16777216;       // 614,400 f
  float* feats = Wt + (size_t)300 * 2048;             // 327,680 f
  (void)ws_size; (void)in_sizes; (void)n_in; (void)out_size;

  k_clear<<<dim3(4096), dim3(256), 0, stream>>>((uint4*)h_ep);
  k_wt<<<dim3(2400), dim3(256), 0, stream>>>(w_ih_f, w_ih_b, Wt);
  k_xproj<<<dim3(256, 16), dim3(256), 0, stream>>>(sentence, table, Wt, b_f,
                                                   b_b, xproj);
  k_lstm<<<dim3(256), dim3(128), 0, stream>>>(w_hh_f, w_hh_b, xproj, h_ep);
  k_feats<<<dim3(256), dim3(256), 0, stream>>>(h_ep, W_out, b_out, feats);
  k_viterbi<<<dim3(64), dim3(64), 0, stream>>>(feats, trans, length, out);
}

// Round 7
// 1749.923 us; speedup vs baseline: 1.2674x; 1.2674x over previous
//
#include <hip/hip_runtime.h>
#include <hip/hip_bf16.h>

#define DINL __device__ __forceinline__

namespace {

typedef unsigned long long u64;

constexpr int Tn = 256;   // sequence length
constexpr int Bn = 64;    // batch
constexpr int HDn = 256;  // per-direction hidden
constexpr int Kt = 20;    // tagset
constexpr int STOPt = 19;
constexpr int STARTt = 18;
constexpr float NEGV = -10000.0f;

DINL float sigm(float x) { return 1.0f / (1.0f + __expf(-x)); }
DINL float tanh_f(float x) {
  float ax = fabsf(x);
  float e = __expf(-2.0f * ax);       // in (0,1]
  float t = (1.0f - e) / (1.0f + e);
  return x < 0.0f ? -t : t;
}

// ---------------- K0: clear handshake flags (replay safety) ------------------
__global__ void k_clear(int4* p) {
  int i = threadIdx.x;          // 512 threads x int4 = 2048 ints
  p[i] = {0, 0, 0, 0};
}

// ---------------- K1: transpose/concat W_ih into Wt[300][2048] ---------------
__global__ void k_wt(const float* __restrict__ wf, const float* __restrict__ wb,
                     float* __restrict__ Wt) {
  int idx = blockIdx.x * 256 + threadIdx.x;
  if (idx >= 300 * 2048) return;
  int k = idx >> 11, n = idx & 2047;
  const float* w = (n < 1024) ? wf : wb;
  int nn = n & 1023;
  Wt[idx] = w[nn * 300 + k];
}

// ---------------- K2: x_proj = gather(embeds) @ W_ih^T + b -------------------
// C[16384, 2048], row m = t*64 + b. Tile 64(M) x 128(N), BK=20, 256 threads.
__global__ __launch_bounds__(256) void k_xproj(
    const int* __restrict__ sentence, const float* __restrict__ table,
    const float* __restrict__ Wt, const float* __restrict__ b_f,
    const float* __restrict__ b_b, float* __restrict__ xproj) {
  __shared__ float As[20][68];    // A^T tile: [kk][row(b)]
  __shared__ float Bs[20][136];   // [kk][col]
  __shared__ int tok[64];

  int tid = threadIdx.x;
  int t = blockIdx.x;             // one time index per M-tile (64 rows = 64 b)
  int n0 = blockIdx.y * 128;

  if (tid < 64) tok[tid] = sentence[tid * Tn + t];  // sentence[b][t]
  __syncthreads();

  int ty = tid >> 4, tx = tid & 15;   // 16x16 threads; micro-tile 4(M) x 8(N)
  float acc[4][8];
#pragma unroll
  for (int i = 0; i < 4; ++i)
#pragma unroll
    for (int j = 0; j < 8; ++j) acc[i][j] = 0.0f;

  for (int k0 = 0; k0 < 300; k0 += 20) {
#pragma unroll
    for (int i = 0; i < 5; ++i) {
      int idx = i * 256 + tid;        // 0..1279
      int r = idx / 20, kk = idx % 20;
      As[kk][r] = table[tok[r] * 300 + k0 + kk];
    }
#pragma unroll
    for (int i = 0; i < 10; ++i) {
      int idx = i * 256 + tid;        // 0..2559
      int kk = idx >> 7, c = idx & 127;
      Bs[kk][c] = Wt[(k0 + kk) * 2048 + n0 + c];
    }
    __syncthreads();
#pragma unroll
    for (int kk = 0; kk < 20; ++kk) {
      float4 a4 = *(const float4*)&As[kk][ty * 4];
      float4 b4a = *(const float4*)&Bs[kk][tx * 8];
      float4 b4b = *(const float4*)&Bs[kk][tx * 8 + 4];
      float av[4] = {a4.x, a4.y, a4.z, a4.w};
      float bvv[8] = {b4a.x, b4a.y, b4a.z, b4a.w, b4b.x, b4b.y, b4b.z, b4b.w};
#pragma unroll
      for (int i = 0; i < 4; ++i)
#pragma unroll
        for (int j = 0; j < 8; ++j) acc[i][j] += av[i] * bvv[j];
    }
    __syncthreads();
  }

  float bias[8];
#pragma unroll
  for (int j = 0; j < 8; ++j) {
    int n = n0 + tx * 8 + j;
    bias[j] = (n < 1024) ? b_f[n] : b_b[n - 1024];
  }
#pragma unroll
  for (int i = 0; i < 4; ++i) {
    size_t m = (size_t)t * 64 + ty * 4 + i;   // row = (t, b=ty*4+i)
    float* dst = &xproj[m * 2048 + n0 + tx * 8];
    float4 v0 = {acc[i][0] + bias[0], acc[i][1] + bias[1], acc[i][2] + bias[2],
                 acc[i][3] + bias[3]};
    float4 v1 = {acc[i][4] + bias[4], acc[i][5] + bias[5], acc[i][6] + bias[6],
                 acc[i][7] + bias[7]};
    *(float4*)dst = v0;
    *(float4*)(dst + 4) = v1;
  }
}

// ---------------- K3: persistent bidirectional LSTM --------------------------
// 256 blocks x 128 thr; GEMV core identical to round 4/6 (W in regs, 16 FMA
// per ds_read_b128, register-halving butterfly). Handshake redesigned:
//   producer: h stores (plain f32, sc1) -> vmcnt(0) drain + barrier ->
//             tid0 publishes per-slice flag (16B-strided, agent relaxed).
//   consumer: wave0's 32 lanes poll the 32 slice flags of its group
//             (128B/iter/block vs r6's 32KB -> no coherence-point congestion),
//             then ONE batched asm read (8x dwordx4 sc1, single waitcnt).
__global__ __launch_bounds__(128) void k_lstm(
    const float* __restrict__ whh_f, const float* __restrict__ whh_b,
    const float* __restrict__ xproj, float* __restrict__ h_all,
    int* __restrict__ flags) {
  __shared__ __align__(16) float hl[16 * 256];  // 16 batches x 256 k (16KB)

  int tid = threadIdx.x;
  int bid = blockIdx.x;
  int gid = bid & 7;        // dir = gid>>2, bg = gid&3 (XCD-affine grouping)
  int s = bid >> 3;         // slice 0..31 (8 hidden cols each)
  int dir = gid >> 2;
  int bg = gid & 3;
  const float* whh = dir ? whh_b : whh_f;

  int c = tid >> 4;         // hidden-col within slice, 0..7
  int kc = tid & 15;        // k-partition (16 interleaved granules of 4)

  // --- W into registers: w4[gate][jj] = W[g*256 + s*8 + c][ (kc+16jj)*4 .. +4 )
  float4 w4[4][4];
#pragma unroll
  for (int g = 0; g < 4; ++g) {
    const float* src = whh + ((size_t)(g * 256 + s * 8 + c)) * 256;
#pragma unroll
    for (int jj = 0; jj < 4; ++jj)
      w4[g][jj] = *(const float4*)(src + ((kc + (jj << 4)) << 2));
  }

  float c_reg = 0.0f;

  for (int st = 0; st < Tn; ++st) {
    int xt = dir ? (Tn - 1 - st) : st;

    // prefetch x-projection gates (independent -> overlaps the poll)
    float xp[4];
    {
      size_t base = ((size_t)(xt * 64 + bg * 16 + kc)) * 2048 + dir * 1024 +
                    s * 8 + c;
#pragma unroll
      for (int g = 0; g < 4; ++g) xp[g] = xproj[base + g * 256];
    }

    float acc[16][4];
#pragma unroll
    for (int b = 0; b < 16; ++b)
#pragma unroll
      for (int g = 0; g < 4; ++g) acc[b][g] = 0.0f;

    if (st > 0) {
      // --- light poll: wave0 lanes watch the 32 slice-flags of this group
      if (tid < 64) {
        const int* fp = flags + ((gid << 5) + (tid & 31)) * 4;
        for (;;) {
          int v = __hip_atomic_load(fp, __ATOMIC_RELAXED,
                                    __HIP_MEMORY_SCOPE_AGENT);
          if (__all((tid < 32) ? (v >= st) : 1)) break;
          __builtin_amdgcn_s_sleep(1);
        }
      }
      __syncthreads();  // B1: flags seen; prev-step hl readers also done

      int pt = dir ? (xt + 1) : (xt - 1);
      const float* hsrc =
          h_all + ((size_t)(dir * Tn + pt) * 64 + bg * 16) * 256;
      // ONE batched read: granule j at float4 index (tid + 128*j),
      // byte = tid*16 + j*2048; 4 pointers (stride 4096B) x offsets {0,2048}.
      const char* tb = (const char*)hsrc + (size_t)tid * 16;
      const char* p0 = tb;
      const char* p1 = tb + 4096;
      const char* p2 = tb + 8192;
      const char* p3 = tb + 12288;
      float4 q0, q1, q2, q3, q4, q5, q6, q7;
      asm volatile(
          "global_load_dwordx4 %0, %8, off sc1\n\t"
          "global_load_dwordx4 %1, %8, off offset:2048 sc1\n\t"
          "global_load_dwordx4 %2, %9, off sc1\n\t"
          "global_load_dwordx4 %3, %9, off offset:2048 sc1\n\t"
          "global_load_dwordx4 %4, %10, off sc1\n\t"
          "global_load_dwordx4 %5, %10, off offset:2048 sc1\n\t"
          "global_load_dwordx4 %6, %11, off sc1\n\t"
          "global_load_dwordx4 %7, %11, off offset:2048 sc1\n\t"
          "s_waitcnt vmcnt(0)"
          : "=&v"(q0), "=&v"(q1), "=&v"(q2), "=&v"(q3), "=&v"(q4), "=&v"(q5),
            "=&v"(q6), "=&v"(q7)
          : "v"(p0), "v"(p1), "v"(p2), "v"(p3));
      // stage: lane-linear strided granules -> conflict-free ds_write_b128
      *(float4*)&hl[(tid + 0 * 128) << 2] = q0;
      *(float4*)&hl[(tid + 1 * 128) << 2] = q1;
      *(float4*)&hl[(tid + 2 * 128) << 2] = q2;
      *(float4*)&hl[(tid + 3 * 128) << 2] = q3;
      *(float4*)&hl[(tid + 4 * 128) << 2] = q4;
      *(float4*)&hl[(tid + 5 * 128) << 2] = q5;
      *(float4*)&hl[(tid + 6 * 128) << 2] = q6;
      *(float4*)&hl[(tid + 7 * 128) << 2] = q7;
      __syncthreads();  // B2: hl ready

      // GEMV: each b128 read feeds 16 FMAs (4 gates x 4 k)
#pragma unroll
      for (int b = 0; b < 16; ++b) {
#pragma unroll
        for (int jj = 0; jj < 4; ++jj) {
          float4 hv = *(const float4*)&hl[b * 256 + ((kc + (jj << 4)) << 2)];
#pragma unroll
          for (int g = 0; g < 4; ++g) {
            acc[b][g] += w4[g][jj].x * hv.x + w4[g][jj].y * hv.y +
                         w4[g][jj].z * hv.z + w4[g][jj].w * hv.w;
          }
        }
      }
    }

    // register-halving butterfly over kc: after round r, entry ii holds
    // b = ii*2^(r+1) + (kc & (2^(r+1)-1)); final: acc[0][g] = gates of b=kc.
#pragma unroll
    for (int r = 0; r < 4; ++r) {
      int m = 1 << r;
      int kb = (kc >> r) & 1;
#pragma unroll
      for (int ii = 0; ii < (16 >> (r + 1)); ++ii) {
#pragma unroll
        for (int g = 0; g < 4; ++g) {
          float e = acc[2 * ii][g], o = acc[2 * ii + 1][g];
          float kept = kb ? o : e;
          float sent = kb ? e : o;
          acc[ii][g] = kept + __shfl_xor(sent, m, 64);
        }
      }
    }

    // update: thread owns (b = kc, col = s*8 + c); gate order i,f,g,o
    {
      float gi = acc[0][0] + xp[0];
      float gf = acc[0][1] + xp[1];
      float gg = acc[0][2] + xp[2];
      float go = acc[0][3] + xp[3];
      c_reg = sigm(gf) * c_reg + sigm(gi) * tanh_f(gg);
      float h = sigm(go) * tanh_f(c_reg);
      __hip_atomic_store(
          &h_all[((size_t)(dir * Tn + xt) * 64 + bg * 16 + kc) * 256 + s * 8 +
                 c],
          h, __ATOMIC_RELAXED, __HIP_MEMORY_SCOPE_AGENT);
    }

    // drain stores, then publish this slice's flag for step st+1
    asm volatile("s_waitcnt vmcnt(0)" ::: "memory");
    __syncthreads();  // B3: every wave's h stores acked at coherence point
    if (tid == 0) {
      __hip_atomic_store(flags + ((gid << 5) + s) * 4, st + 1,
                         __ATOMIC_RELAXED, __HIP_MEMORY_SCOPE_AGENT);
    }
  }
}

// ---------------- K4: feats = concat(hf,hb) @ W_out^T + b_out ----------------
__global__ __launch_bounds__(256) void k_feats(const float* __restrict__ h_all,
                                               const float* __restrict__ Wout,
                                               const float* __restrict__ bout,
                                               float* __restrict__ feats) {
  __shared__ float Wl[20 * 512];   // 40KB
  __shared__ float hlf[64 * 256];  // 64KB, XOR-swizzled

  int tid = threadIdx.x;
  int t = blockIdx.x;
  for (int i = tid; i < 20 * 512; i += 256) Wl[i] = Wout[i];

  float acc[5] = {0, 0, 0, 0, 0};
  int b = tid & 63, kg5 = tid >> 6;
  int swz = b & 7;

  for (int d = 0; d < 2; ++d) {
    __syncthreads();
    const float* hsrc = h_all + ((size_t)(d * Tn + t)) * 64 * 256;
#pragma unroll 8
    for (int i = 0; i < 64; ++i) {
      int idx = i * 256 + tid;
      int hb = idx >> 8, k = idx & 255;
      hlf[hb * 256 + 4 * ((k >> 2) ^ (hb & 7)) + (k & 3)] = hsrc[idx];
    }
    __syncthreads();
    for (int jg = 0; jg < 64; ++jg) {
      float4 hv = *(const float4*)&hlf[b * 256 + 4 * (jg ^ swz)];
#pragma unroll
      for (int kk = 0; kk < 5; ++kk) {
        int krow = kg5 * 5 + kk;
        float4 wvv = *(const float4*)&Wl[krow * 512 + d * 256 + jg * 4];
        acc[kk] += hv.x * wvv.x + hv.y * wvv.y + hv.z * wvv.z + hv.w * wvv.w;
      }
    }
  }
#pragma unroll
  for (int kk = 0; kk < 5; ++kk) {
    int krow = kg5 * 5 + kk;
    feats[((size_t)b * Tn + t) * Kt + krow] = acc[kk] + bout[krow];
  }
}

// ---------------- K5: Viterbi decode, one wave per batch element -------------
__global__ __launch_bounds__(64) void k_viterbi(const float* __restrict__ feats,
                                                const float* __restrict__ trans,
                                                const int* __restrict__ length,
                                                float* __restrict__ out) {
  __shared__ float tr[400];
  __shared__ float fv[20];
  __shared__ float term[20];
  __shared__ unsigned char bps[256][20];

  int b = blockIdx.x;
  int lane = threadIdx.x;
  for (int i = lane; i < 400; i += 64) tr[i] = trans[i];
  if (lane < 20) fv[lane] = (lane == STARTt) ? 0.0f : NEGV;
  int len = length[b];
  __syncthreads();

  for (int t = 0; t < Tn; ++t) {
    float nf = 0.0f;
    int bp = 0;
    if (lane < 20) {
      if (t < len) {
        float vmax = -3.4e38f;
        int pb = 0;
#pragma unroll
        for (int p = 0; p < 20; ++p) {
          float v = fv[p] + tr[lane * 20 + p];
          if (v > vmax) { vmax = v; pb = p; }   // strict > == first-argmax
        }
        nf = vmax + feats[((size_t)b * Tn + t) * Kt + lane];
        bp = pb;
      } else {
        nf = fv[lane];
        bp = lane;
      }
    }
    __syncthreads();
    if (lane < 20) {
      fv[lane] = nf;
      bps[t][lane] = (unsigned char)bp;
    }
    __syncthreads();
  }

  if (lane < 20) term[lane] = fv[lane] + tr[STOPt * 20 + lane];
  __syncthreads();
  if (lane == 0) {
    float smax = term[0];
    int last = 0;
    for (int p = 1; p < 20; ++p)
      if (term[p] > smax) { smax = term[p]; last = p; }
    out[b] = smax;                     // viterbi score
    int tag = last;
    for (int t = Tn - 1; t >= 0; --t) {
      out[64 + b * Tn + t] = (float)tag;
      tag = bps[t][tag];
    }
  }
}

}  // namespace

extern "C" void kernel_launch(void* const* d_in, const int* in_sizes, int n_in,
                              void* d_out, int out_size, void* d_ws,
                              size_t ws_size, hipStream_t stream) {
  const int* sentence = (const int*)d_in[0];
  const int* length = (const int*)d_in[1];
  const float* table = (const float*)d_in[2];
  const float* w_ih_f = (const float*)d_in[3];
  const float* w_hh_f = (const float*)d_in[4];
  const float* b_f = (const float*)d_in[5];
  const float* w_ih_b = (const float*)d_in[6];
  const float* w_hh_b = (const float*)d_in[7];
  const float* b_b = (const float*)d_in[8];
  const float* W_out = (const float*)d_in[9];
  const float* b_out = (const float*)d_in[10];
  const float* trans = (const float*)d_in[11];
  float* out = (float*)d_out;

  // workspace layout (floats)
  float* ws = (float*)d_ws;
  float* xproj = ws;                                  // 33,554,432 f
  float* h_all = ws + (size_t)33554432;               // 8,388,608 f (33.5 MB)
  float* Wt = h_all + (size_t)8388608;                // 614,400 f
  float* feats = Wt + (size_t)300 * 2048;             // 327,680 f
  int* flags = (int*)(feats + (size_t)Bn * Tn * Kt);  // 2048 ints (16B-strided)
  (void)ws_size; (void)in_sizes; (void)n_in; (void)out_size;

  k_clear<<<dim3(1), dim3(512), 0, stream>>>((int4*)flags);
  k_wt<<<dim3(2400), dim3(256), 0, stream>>>(w_ih_f, w_ih_b, Wt);
  k_xproj<<<dim3(256, 16), dim3(256), 0, stream>>>(sentence, table, Wt, b_f,
                                                   b_b, xproj);
  k_lstm<<<dim3(256), dim3(128), 0, stream>>>(w_hh_f, w_hh_b, xproj, h_all,
                                              flags);
  k_feats<<<dim3(256), dim3(256), 0, stream>>>(h_all, W_out, b_out, feats);
  k_viterbi<<<dim3(64), dim3(64), 0, stream>>>(feats, trans, length, out);
}

// Round 8
// 1480.089 us; speedup vs baseline: 1.4985x; 1.1823x over previous
//
#include <hip/hip_runtime.h>
#include <hip/hip_bf16.h>

#define DINL __device__ __forceinline__

namespace {

typedef unsigned long long u64;

constexpr int Tn = 256;   // sequence length
constexpr int Bn = 64;    // batch
constexpr int HDn = 256;  // per-direction hidden
constexpr int Kt = 20;    // tagset
constexpr int STOPt = 19;
constexpr int STARTt = 18;
constexpr float NEGV = -10000.0f;

DINL float sigm(float x) { return 1.0f / (1.0f + __expf(-x)); }
DINL float tanh_f(float x) {
  float ax = fabsf(x);
  float e = __expf(-2.0f * ax);       // in (0,1]
  float t = (1.0f - e) / (1.0f + e);
  return x < 0.0f ? -t : t;
}

// ---------------- K0: bump per-launch epoch (replay disambiguation) ----------
// Monotonic per launch (graph replays run it once each). Start value may be
// poison garbage; only monotonicity matters (windowed compares below).
__global__ void k_epoch(unsigned* ep) {
  if (threadIdx.x == 0)
    __hip_atomic_fetch_add(ep, 1u, __ATOMIC_RELAXED, __HIP_MEMORY_SCOPE_AGENT);
}

// ---------------- K1: transpose/concat W_ih into Wt[300][2048] ---------------
__global__ void k_wt(const float* __restrict__ wf, const float* __restrict__ wb,
                     float* __restrict__ Wt) {
  int idx = blockIdx.x * 256 + threadIdx.x;
  if (idx >= 300 * 2048) return;
  int k = idx >> 11, n = idx & 2047;
  const float* w = (n < 1024) ? wf : wb;
  int nn = n & 1023;
  Wt[idx] = w[nn * 300 + k];
}

// ---------------- K2: x_proj = gather(embeds) @ W_ih^T + b -------------------
// C[16384, 2048], row m = t*64 + b. Tile 64(M) x 128(N), BK=20, 256 threads.
__global__ __launch_bounds__(256) void k_xproj(
    const int* __restrict__ sentence, const float* __restrict__ table,
    const float* __restrict__ Wt, const float* __restrict__ b_f,
    const float* __restrict__ b_b, float* __restrict__ xproj) {
  __shared__ float As[20][68];    // A^T tile: [kk][row(b)]
  __shared__ float Bs[20][136];   // [kk][col]
  __shared__ int tok[64];

  int tid = threadIdx.x;
  int t = blockIdx.x;             // one time index per M-tile (64 rows = 64 b)
  int n0 = blockIdx.y * 128;

  if (tid < 64) tok[tid] = sentence[tid * Tn + t];  // sentence[b][t]
  __syncthreads();

  int ty = tid >> 4, tx = tid & 15;   // 16x16 threads; micro-tile 4(M) x 8(N)
  float acc[4][8];
#pragma unroll
  for (int i = 0; i < 4; ++i)
#pragma unroll
    for (int j = 0; j < 8; ++j) acc[i][j] = 0.0f;

  for (int k0 = 0; k0 < 300; k0 += 20) {
#pragma unroll
    for (int i = 0; i < 5; ++i) {
      int idx = i * 256 + tid;        // 0..1279
      int r = idx / 20, kk = idx % 20;
      As[kk][r] = table[tok[r] * 300 + k0 + kk];
    }
#pragma unroll
    for (int i = 0; i < 10; ++i) {
      int idx = i * 256 + tid;        // 0..2559
      int kk = idx >> 7, c = idx & 127;
      Bs[kk][c] = Wt[(k0 + kk) * 2048 + n0 + c];
    }
    __syncthreads();
#pragma unroll
    for (int kk = 0; kk < 20; ++kk) {
      float4 a4 = *(const float4*)&As[kk][ty * 4];
      float4 b4a = *(const float4*)&Bs[kk][tx * 8];
      float4 b4b = *(const float4*)&Bs[kk][tx * 8 + 4];
      float av[4] = {a4.x, a4.y, a4.z, a4.w};
      float bvv[8] = {b4a.x, b4a.y, b4a.z, b4a.w, b4b.x, b4b.y, b4b.z, b4b.w};
#pragma unroll
      for (int i = 0; i < 4; ++i)
#pragma unroll
        for (int j = 0; j < 8; ++j) acc[i][j] += av[i] * bvv[j];
    }
    __syncthreads();
  }

  float bias[8];
#pragma unroll
  for (int j = 0; j < 8; ++j) {
    int n = n0 + tx * 8 + j;
    bias[j] = (n < 1024) ? b_f[n] : b_b[n - 1024];
  }
#pragma unroll
  for (int i = 0; i < 4; ++i) {
    size_t m = (size_t)t * 64 + ty * 4 + i;   // row = (t, b=ty*4+i)
    float* dst = &xproj[m * 2048 + n0 + tx * 8];
    float4 v0 = {acc[i][0] + bias[0], acc[i][1] + bias[1], acc[i][2] + bias[2],
                 acc[i][3] + bias[3]};
    float4 v1 = {acc[i][4] + bias[4], acc[i][5] + bias[5], acc[i][6] + bias[6],
                 acc[i][7] + bias[7]};
    *(float4*)dst = v0;
    *(float4*)(dst + 4) = v1;
  }
}

// ---------------- K3: persistent bidirectional LSTM --------------------------
// 256 blocks x 128 thr; GEMV core identical to rounds 4-7. NEW: scope-adaptive
// handshake. gid = bid&7 groups land on ONE XCD under the %8 round-robin ->
// one-time consensus (s_getreg XCC_ID, agent-exchanged, epoch-tagged) picks:
//   FAST (all 32 blocks same XCD): producer h + flag via PLAIN stores (dirty
//     in the shared per-XCD L2, vmcnt ack ~250cyc). Consumers keep sc1 loads,
//     which probe the local L2 en route to L3 -> L2-latency hops end to end.
//   SLOW (mapping violated): round-7 sc1 protocol (correct on any placement).
// Flags carry E*256+step (E = per-launch epoch) with windowed compare ->
// stale lines from earlier replays can never false-positive.
__global__ __launch_bounds__(128) void k_lstm(
    const float* __restrict__ whh_f, const float* __restrict__ whh_b,
    const float* __restrict__ xproj, float* __restrict__ h_all,
    int* __restrict__ flags, int* __restrict__ xcdtab,
    const unsigned* __restrict__ ep) {
  __shared__ __align__(16) float hl[16 * 256];  // 16 batches x 256 k (16KB)
  __shared__ int fastsh;

  int tid = threadIdx.x;
  int bid = blockIdx.x;
  int gid = bid & 7;        // dir = gid>>2, bg = gid&3 (XCD-affine grouping)
  int s = bid >> 3;         // slice 0..31 (8 hidden cols each)
  int dir = gid >> 2;
  int bg = gid & 3;
  const float* whh = dir ? whh_b : whh_f;

  int c = tid >> 4;         // hidden-col within slice, 0..7
  int kc = tid & 15;        // k-partition (16 interleaved granules of 4)

  // --- per-launch epoch + XCD consensus --------------------------------------
  unsigned E =
      __hip_atomic_load(ep, __ATOMIC_RELAXED, __HIP_MEMORY_SCOPE_AGENT);
  // s_getreg_b32 imm = (size-1)<<11 | offset<<6 | id ; XCC_ID: id=20, [3:0]
  unsigned xcd = __builtin_amdgcn_s_getreg((3 << 11) | (0 << 6) | 20) & 0xFu;
  if (tid == 0) {
    __hip_atomic_store(&xcdtab[(gid << 5) + s],
                       (int)((E << 4) | xcd), __ATOMIC_RELAXED,
                       __HIP_MEMORY_SCOPE_AGENT);
  }
  if (tid < 64) {
    const int* xp_ = xcdtab + (gid << 5) + (tid & 31);
    unsigned v;
    for (;;) {
      v = (unsigned)__hip_atomic_load(xp_, __ATOMIC_RELAXED,
                                      __HIP_MEMORY_SCOPE_AGENT);
      bool rdy = (v >> 4) == (E & 0x0FFFFFFFu);
      if (__all((tid < 32) ? rdy : 1)) break;
      __builtin_amdgcn_s_sleep(1);
    }
    int mine = (int)(v & 0xFu);
    int ref = __shfl(mine, 0, 64);
    bool eq = (mine == ref);
    bool alleq = __all((tid < 32) ? eq : 1);
    if (tid == 0) fastsh = alleq ? 1 : 0;
  }

  // --- W into registers: w4[gate][jj] = W[g*256 + s*8 + c][ (kc+16jj)*4 .. +4 )
  float4 w4[4][4];
#pragma unroll
  for (int g = 0; g < 4; ++g) {
    const float* src = whh + ((size_t)(g * 256 + s * 8 + c)) * 256;
#pragma unroll
    for (int jj = 0; jj < 4; ++jj)
      w4[g][jj] = *(const float4*)(src + ((kc + (jj << 4)) << 2));
  }

  __syncthreads();
  const bool fast = (fastsh != 0);
  const unsigned base = E * 256u;

  float c_reg = 0.0f;

  for (int st = 0; st < Tn; ++st) {
    int xt = dir ? (Tn - 1 - st) : st;

    // prefetch x-projection gates (independent -> overlaps the poll)
    float xp[4];
    {
      size_t xb = ((size_t)(xt * 64 + bg * 16 + kc)) * 2048 + dir * 1024 +
                  s * 8 + c;
#pragma unroll
      for (int g = 0; g < 4; ++g) xp[g] = xproj[xb + g * 256];
    }

    float acc[16][4];
#pragma unroll
    for (int b = 0; b < 16; ++b)
#pragma unroll
      for (int g = 0; g < 4; ++g) acc[b][g] = 0.0f;

    if (st > 0) {
      // --- light poll: wave0 lanes watch the 32 slice-flags of this group.
      // sc1 load probes the local L2 first -> L2 latency in fast mode.
      if (tid < 64) {
        const int* fp = flags + ((gid << 5) + (tid & 31)) * 4;
        for (;;) {
          unsigned v = (unsigned)__hip_atomic_load(
              fp, __ATOMIC_RELAXED, __HIP_MEMORY_SCOPE_AGENT);
          int d = (int)(v - base);   // windowed: stale epochs give d <= 0
          if (__all((tid < 32) ? (d >= st) : 1)) break;
          __builtin_amdgcn_s_sleep(1);
        }
      }
      __syncthreads();  // B1: flags seen; prev-step hl readers also done

      int pt = dir ? (xt + 1) : (xt - 1);
      const float* hsrc =
          h_all + ((size_t)(dir * Tn + pt) * 64 + bg * 16) * 256;
      // ONE batched read: granule j at float4 index (tid + 128*j),
      // byte = tid*16 + j*2048; 4 pointers (stride 4096B) x offsets {0,2048}.
      const char* tb = (const char*)hsrc + (size_t)tid * 16;
      const char* p0 = tb;
      const char* p1 = tb + 4096;
      const char* p2 = tb + 8192;
      const char* p3 = tb + 12288;
      float4 q0, q1, q2, q3, q4, q5, q6, q7;
      asm volatile(
          "global_load_dwordx4 %0, %8, off sc1\n\t"
          "global_load_dwordx4 %1, %8, off offset:2048 sc1\n\t"
          "global_load_dwordx4 %2, %9, off sc1\n\t"
          "global_load_dwordx4 %3, %9, off offset:2048 sc1\n\t"
          "global_load_dwordx4 %4, %10, off sc1\n\t"
          "global_load_dwordx4 %5, %10, off offset:2048 sc1\n\t"
          "global_load_dwordx4 %6, %11, off sc1\n\t"
          "global_load_dwordx4 %7, %11, off offset:2048 sc1\n\t"
          "s_waitcnt vmcnt(0)"
          : "=&v"(q0), "=&v"(q1), "=&v"(q2), "=&v"(q3), "=&v"(q4), "=&v"(q5),
            "=&v"(q6), "=&v"(q7)
          : "v"(p0), "v"(p1), "v"(p2), "v"(p3));
      // stage: lane-linear strided granules -> conflict-free ds_write_b128
      *(float4*)&hl[(tid + 0 * 128) << 2] = q0;
      *(float4*)&hl[(tid + 1 * 128) << 2] = q1;
      *(float4*)&hl[(tid + 2 * 128) << 2] = q2;
      *(float4*)&hl[(tid + 3 * 128) << 2] = q3;
      *(float4*)&hl[(tid + 4 * 128) << 2] = q4;
      *(float4*)&hl[(tid + 5 * 128) << 2] = q5;
      *(float4*)&hl[(tid + 6 * 128) << 2] = q6;
      *(float4*)&hl[(tid + 7 * 128) << 2] = q7;
      __syncthreads();  // B2: hl ready

      // GEMV: each b128 read feeds 16 FMAs (4 gates x 4 k)
#pragma unroll
      for (int b = 0; b < 16; ++b) {
#pragma unroll
        for (int jj = 0; jj < 4; ++jj) {
          float4 hv = *(const float4*)&hl[b * 256 + ((kc + (jj << 4)) << 2)];
#pragma unroll
          for (int g = 0; g < 4; ++g) {
            acc[b][g] += w4[g][jj].x * hv.x + w4[g][jj].y * hv.y +
                         w4[g][jj].z * hv.z + w4[g][jj].w * hv.w;
          }
        }
      }
    }

    // register-halving butterfly over kc: after round r, entry ii holds
    // b = ii*2^(r+1) + (kc & (2^(r+1)-1)); final: acc[0][g] = gates of b=kc.
#pragma unroll
    for (int r = 0; r < 4; ++r) {
      int m = 1 << r;
      int kb = (kc >> r) & 1;
#pragma unroll
      for (int ii = 0; ii < (16 >> (r + 1)); ++ii) {
#pragma unroll
        for (int g = 0; g < 4; ++g) {
          float e = acc[2 * ii][g], o = acc[2 * ii + 1][g];
          float kept = kb ? o : e;
          float sent = kb ? e : o;
          acc[ii][g] = kept + __shfl_xor(sent, m, 64);
        }
      }
    }

    // update: thread owns (b = kc, col = s*8 + c); gate order i,f,g,o
    {
      float gi = acc[0][0] + xp[0];
      float gf = acc[0][1] + xp[1];
      float gg = acc[0][2] + xp[2];
      float go = acc[0][3] + xp[3];
      c_reg = sigm(gf) * c_reg + sigm(gi) * tanh_f(gg);
      float h = sigm(go) * tanh_f(c_reg);
      size_t hi = ((size_t)(dir * Tn + xt) * 64 + bg * 16 + kc) * 256 + s * 8 +
                  c;
      if (fast) {
        h_all[hi] = h;   // plain: dirty in the group's (shared) L2
      } else {
        __hip_atomic_store(&h_all[hi], h, __ATOMIC_RELAXED,
                           __HIP_MEMORY_SCOPE_AGENT);
      }
    }

    // drain stores (fast: L2 ack; slow: coherence-point ack), then publish
    asm volatile("s_waitcnt vmcnt(0)" ::: "memory");
    __syncthreads();  // B3: every wave's h stores drained
    if (tid == 0) {
      int fv = (int)(base + (unsigned)(st + 1));
      if (fast) {
        flags[((gid << 5) + s) * 4] = fv;
      } else {
        __hip_atomic_store(flags + ((gid << 5) + s) * 4, fv, __ATOMIC_RELAXED,
                           __HIP_MEMORY_SCOPE_AGENT);
      }
    }
  }
}

// ---------------- K4: feats = concat(hf,hb) @ W_out^T + b_out ----------------
__global__ __launch_bounds__(256) void k_feats(const float* __restrict__ h_all,
                                               const float* __restrict__ Wout,
                                               const float* __restrict__ bout,
                                               float* __restrict__ feats) {
  __shared__ float Wl[20 * 512];   // 40KB
  __shared__ float hlf[64 * 256];  // 64KB, XOR-swizzled

  int tid = threadIdx.x;
  int t = blockIdx.x;
  for (int i = tid; i < 20 * 512; i += 256) Wl[i] = Wout[i];

  float acc[5] = {0, 0, 0, 0, 0};
  int b = tid & 63, kg5 = tid >> 6;
  int swz = b & 7;

  for (int d = 0; d < 2; ++d) {
    __syncthreads();
    const float* hsrc = h_all + ((size_t)(d * Tn + t)) * 64 * 256;
#pragma unroll 8
    for (int i = 0; i < 64; ++i) {
      int idx = i * 256 + tid;
      int hb = idx >> 8, k = idx & 255;
      hlf[hb * 256 + 4 * ((k >> 2) ^ (hb & 7)) + (k & 3)] = hsrc[idx];
    }
    __syncthreads();
    for (int jg = 0; jg < 64; ++jg) {
      float4 hv = *(const float4*)&hlf[b * 256 + 4 * (jg ^ swz)];
#pragma unroll
      for (int kk = 0; kk < 5; ++kk) {
        int krow = kg5 * 5 + kk;
        float4 wvv = *(const float4*)&Wl[krow * 512 + d * 256 + jg * 4];
        acc[kk] += hv.x * wvv.x + hv.y * wvv.y + hv.z * wvv.z + hv.w * wvv.w;
      }
    }
  }
#pragma unroll
  for (int kk = 0; kk < 5; ++kk) {
    int krow = kg5 * 5 + kk;
    feats[((size_t)b * Tn + t) * Kt + krow] = acc[kk] + bout[krow];
  }
}

// ---------------- K5: Viterbi decode, one wave per batch element -------------
__global__ __launch_bounds__(64) void k_viterbi(const float* __restrict__ feats,
                                                const float* __restrict__ trans,
                                                const int* __restrict__ length,
                                                float* __restrict__ out) {
  __shared__ float tr[400];
  __shared__ float fv[20];
  __shared__ float term[20];
  __shared__ unsigned char bps[256][20];

  int b = blockIdx.x;
  int lane = threadIdx.x;
  for (int i = lane; i < 400; i += 64) tr[i] = trans[i];
  if (lane < 20) fv[lane] = (lane == STARTt) ? 0.0f : NEGV;
  int len = length[b];
  __syncthreads();

  for (int t = 0; t < Tn; ++t) {
    float nf = 0.0f;
    int bp = 0;
    if (lane < 20) {
      if (t < len) {
        float vmax = -3.4e38f;
        int pb = 0;
#pragma unroll
        for (int p = 0; p < 20; ++p) {
          float v = fv[p] + tr[lane * 20 + p];
          if (v > vmax) { vmax = v; pb = p; }   // strict > == first-argmax
        }
        nf = vmax + feats[((size_t)b * Tn + t) * Kt + lane];
        bp = pb;
      } else {
        nf = fv[lane];
        bp = lane;
      }
    }
    __syncthreads();
    if (lane < 20) {
      fv[lane] = nf;
      bps[t][lane] = (unsigned char)bp;
    }
    __syncthreads();
  }

  if (lane < 20) term[lane] = fv[lane] + tr[STOPt * 20 + lane];
  __syncthreads();
  if (lane == 0) {
    float smax = term[0];
    int last = 0;
    for (int p = 1; p < 20; ++p)
      if (term[p] > smax) { smax = term[p]; last = p; }
    out[b] = smax;                     // viterbi score
    int tag = last;
    for (int t = Tn - 1; t >= 0; --t) {
      out[64 + b * Tn + t] = (float)tag;
      tag = bps[t][tag];
    }
  }
}

}  // namespace

extern "C" void kernel_launch(void* const* d_in, const int* in_sizes, int n_in,
                              void* d_out, int out_size, void* d_ws,
                              size_t ws_size, hipStream_t stream) {
  const int* sentence = (const int*)d_in[0];
  const int* length = (const int*)d_in[1];
  const float* table = (const float*)d_in[2];
  const float* w_ih_f = (const float*)d_in[3];
  const float* w_hh_f = (const float*)d_in[4];
  const float* b_f = (const float*)d_in[5];
  const float* w_ih_b = (const float*)d_in[6];
  const float* w_hh_b = (const float*)d_in[7];
  const float* b_b = (const float*)d_in[8];
  const float* W_out = (const float*)d_in[9];
  const float* b_out = (const float*)d_in[10];
  const float* trans = (const float*)d_in[11];
  float* out = (float*)d_out;

  // workspace layout (floats)
  float* ws = (float*)d_ws;
  float* xproj = ws;                                  // 33,554,432 f
  float* h_all = ws + (size_t)33554432;               // 8,388,608 f (33.5 MB)
  float* Wt = h_all + (size_t)8388608;                // 614,400 f
  float* feats = Wt + (size_t)300 * 2048;             // 327,680 f
  int* flags = (int*)(feats + (size_t)Bn * Tn * Kt);  // 1024 ints (16B-strided)
  int* xcdtab = flags + 1024;                         // 256 ints
  unsigned* ep = (unsigned*)(xcdtab + 256);           // 1 int epoch
  (void)ws_size; (void)in_sizes; (void)n_in; (void)out_size;

  k_epoch<<<dim3(1), dim3(64), 0, stream>>>(ep);
  k_wt<<<dim3(2400), dim3(256), 0, stream>>>(w_ih_f, w_ih_b, Wt);
  k_xproj<<<dim3(256, 16), dim3(256), 0, stream>>>(sentence, table, Wt, b_f,
                                                   b_b, xproj);
  k_lstm<<<dim3(256), dim3(128), 0, stream>>>(w_hh_f, w_hh_b, xproj, h_all,
                                              flags, xcdtab, ep);
  k_feats<<<dim3(256), dim3(256), 0, stream>>>(h_all, W_out, b_out, feats);
  k_viterbi<<<dim3(64), dim3(64), 0, stream>>>(feats, trans, length, out);
}